// Round 1
// baseline (2313.202 us; speedup 1.0000x reference)
//
#include <hip/hip_runtime.h>
#include <hip/hip_bf16.h>
#include <stdint.h>

typedef __hip_bfloat16 bf16;
typedef __attribute__((ext_vector_type(8))) short short8;
typedef __attribute__((ext_vector_type(4))) float f32x4;

#define INFV 1e12f

// problem dims
constexpr int Vv = 45000;
constexpr int VE = 45010;

static __device__ __forceinline__ float bf2f(unsigned short u){
  union{ unsigned int i; float f; } w; w.i = ((unsigned int)u) << 16; return w.f;
}
static __device__ __forceinline__ unsigned short f2bf(float x){
  union { __hip_bfloat16 h; unsigned short u; } w; w.h = __float2bfloat16(x); return w.u;
}

// ---------------------------------------------------------------------------
// Generic f32 tiled GEMM: C[M,N] = A[M,K] @ B[K,N] (+bias) (optional tanh+bf16 out)
// A may be a concat of two row-major sources split at column Ksplit.
// ---------------------------------------------------------------------------
template<bool ABF16, bool TANHOUT>
__launch_bounds__(256)
__global__ void k_gemm(const void* __restrict__ Ap, const void* __restrict__ Ap2, int Ksplit,
                       const float* __restrict__ Bp, const float* __restrict__ bias,
                       void* __restrict__ Cp, int M, int N, int K)
{
  __shared__ float As[16][68];
  __shared__ float Bs[16][68];
  int tid = threadIdx.x;
  int tx = tid & 15, ty = tid >> 4;
  int m0 = blockIdx.y * 64, n0 = blockIdx.x * 64;
  float acc[4][4] = {};
  for (int kc = 0; kc < K; kc += 16){
    for (int idx = tid; idx < 64*16; idx += 256){
      int r = idx >> 4, c = idx & 15;
      int gr = m0 + r, gk = kc + c;
      float v = 0.f;
      if (gr < M && gk < K){
        if (ABF16)            v = bf2f(((const unsigned short*)Ap)[(size_t)gr*K + gk]);
        else if (gk < Ksplit) v = ((const float*)Ap )[(size_t)gr*Ksplit + gk];
        else                  v = ((const float*)Ap2)[(size_t)gr*(K - Ksplit) + (gk - Ksplit)];
      }
      As[c][r] = v;
    }
    for (int idx = tid; idx < 16*64; idx += 256){
      int r = idx >> 6, c = idx & 63;
      int gk = kc + r, gn = n0 + c;
      Bs[r][c] = (gk < K && gn < N) ? Bp[(size_t)gk*N + gn] : 0.f;
    }
    __syncthreads();
    #pragma unroll
    for (int kk = 0; kk < 16; ++kk){
      float a[4], b[4];
      #pragma unroll
      for (int i = 0; i < 4; ++i) a[i] = As[kk][ty*4 + i];
      #pragma unroll
      for (int j = 0; j < 4; ++j) b[j] = Bs[kk][tx*4 + j];
      #pragma unroll
      for (int i = 0; i < 4; ++i)
        #pragma unroll
        for (int j = 0; j < 4; ++j) acc[i][j] = fmaf(a[i], b[j], acc[i][j]);
    }
    __syncthreads();
  }
  for (int i = 0; i < 4; ++i){
    int gr = m0 + ty*4 + i; if (gr >= M) continue;
    for (int j = 0; j < 4; ++j){
      int gn = n0 + tx*4 + j; if (gn >= N) continue;
      float v = acc[i][j] + (bias ? bias[gn] : 0.f);
      if (TANHOUT) ((unsigned short*)Cp)[(size_t)gr*N + gn] = f2bf(tanhf(v));
      else         ((float*)Cp)[(size_t)gr*N + gn] = v;
    }
  }
}

// ---------------------------------------------------------------------------
// small prep kernels
// ---------------------------------------------------------------------------
__global__ void k_cvt(const float* __restrict__ src, unsigned short* __restrict__ dst, int n){
  int i = blockIdx.x*256 + threadIdx.x;
  if (i < n) dst[i] = f2bf(src[i]);
}

__global__ void k_gather(const int* __restrict__ trg, const float* __restrict__ emb,
                         float* __restrict__ EmbA){
  int i = blockIdx.x*256 + threadIdx.x;
  if (i >= 1024*300) return;
  int r = i / 300, e = i - r*300;
  EmbA[i] = emb[(size_t)trg[r]*300 + e];
}

__global__ void k_bsum(const float* __restrict__ a, const float* __restrict__ b,
                       float* __restrict__ o){
  int i = blockIdx.x*256 + threadIdx.x;
  if (i < 2048) o[i] = a[i] + b[i];
}

// WgT[c'][k] = bf16 of [Wf;W_hh][k][c], c' = 4*h+q <-> c = 512*q+h (quad-interleaved cols)
__global__ void k_wgt(const float* __restrict__ Wf, const float* __restrict__ W_hh,
                      unsigned short* __restrict__ WgT){
  int idx = blockIdx.x*256 + threadIdx.x;
  if (idx >= 2048*1024) return;
  int cp = idx >> 10, k = idx & 1023;
  int c = (cp & 3)*512 + (cp >> 2);
  float v = (k < 512) ? Wf[(size_t)k*2048 + c] : W_hh[(size_t)(k-512)*2048 + c];
  WgT[idx] = f2bf(v);
}

// WoT[n][k] = bf16(W_out[k][n]) for n<45000, 0 for padded rows; LDS-tiled transpose
__launch_bounds__(256)
__global__ void k_wot(const float* __restrict__ W_out, unsigned short* __restrict__ WoT){
  __shared__ float tl[64][65];
  int n0 = blockIdx.x * 64;  // 704
  int k0 = blockIdx.y * 64;  // 8
  int tid = threadIdx.x;
  for (int idx = tid; idx < 64*64; idx += 256){
    int r = idx >> 6, c = idx & 63;       // r=k-local, c=n-local
    int gn = n0 + c;
    tl[r][c] = (gn < Vv) ? W_out[(size_t)(k0 + r)*Vv + gn] : 0.f;
  }
  __syncthreads();
  for (int idx = tid; idx < 64*64; idx += 256){
    int r = idx >> 6, c = idx & 63;       // r=n-local, c=k-local
    WoT[(size_t)(n0 + r)*512 + k0 + c] = f2bf(tl[c][r]);
  }
}

__global__ void k_init(const float* __restrict__ h0, const float* __restrict__ c0,
                       unsigned short* __restrict__ HCa, float* __restrict__ Cst){
  int i = blockIdx.x*256 + threadIdx.x;
  if (i < 32*1024){
    int b = i >> 10, k = i & 1023;
    HCa[i] = (k < 512) ? f2bf(0.f) : f2bf(h0[b*512 + (k - 512)]);
  }
  if (i < 32*512) Cst[i] = c0[i];
}

// ---------------------------------------------------------------------------
// recurrence step 1: gates = G1[:,t] + [ctx|h] @ WgT^T, LSTM cell -> h,c
// grid 32 blocks x 256 thr; block owns 64 permuted gate-cols (16 h indices)
// ---------------------------------------------------------------------------
__launch_bounds__(256, 1)
__global__ void k_gates(const unsigned short* __restrict__ WgT,
                        const unsigned short* __restrict__ HCprev,
                        unsigned short* __restrict__ HCnext,
                        float* __restrict__ C_state,
                        const float* __restrict__ G1,
                        unsigned short* __restrict__ HCz,
                        int t)
{
  __shared__ char Bsm[64*272];   // 64 rows x 256B, pitch 272 to spread banks
  int tid = threadIdx.x;
  int lane = tid & 63, w2 = tid >> 6;
  int blk = blockIdx.x;
  int l15 = lane & 15, lh = lane >> 4;
  f32x4 zero = {0.f,0.f,0.f,0.f};
  f32x4 acc0 = zero, acc1 = zero;
  const char* Ab = (const char*)HCprev;

  for (int kc = 0; kc < 1024; kc += 128){
    #pragma unroll
    for (int call = 0; call < 4; ++call){
      int o = call*4096 + tid*16;
      int r = o >> 8, cb = o & 255;
      short8 v = *(const short8*)((const char*)WgT + (size_t)(blk*64 + r)*2048 + kc*2 + cb);
      *(short8*)(Bsm + r*272 + cb) = v;
    }
    __syncthreads();
    #pragma unroll
    for (int ks = 0; ks < 4; ++ks){
      short8 a0 = *(const short8*)(Ab + (size_t)l15*2048      + (kc + ks*32)*2 + lh*16);
      short8 a1 = *(const short8*)(Ab + (size_t)(l15+16)*2048 + (kc + ks*32)*2 + lh*16);
      int br = w2*16 + l15;
      short8 bfr = *(const short8*)(Bsm + br*272 + ks*64 + lh*16);
      acc0 = __builtin_amdgcn_mfma_f32_16x16x32_bf16(a0, bfr, acc0, 0, 0, 0);
      acc1 = __builtin_amdgcn_mfma_f32_16x16x32_bf16(a1, bfr, acc1, 0, 0, 0);
    }
    __syncthreads();
  }

  int cg = blk*64 + w2*16 + l15;     // permuted gate col
  int hfull = cg >> 2, q = cg & 3;   // q: 0=i 1=f 2=g 3=o
  #pragma unroll
  for (int f = 0; f < 2; ++f){
    #pragma unroll
    for (int j = 0; j < 4; ++j){
      int b = f*16 + 4*lh + j;
      float g = (f ? acc1[j] : acc0[j]) + G1[((size_t)b*32 + t)*2048 + q*512 + hfull];
      float x1 = (q == 2) ? tanhf(g) : 1.f/(1.f + expf(-g));
      float xg = __shfl_xor(x1, 2);  // from q^2
      float xf = __shfl_xor(x1, 1);  // from q^1
      float xo = __shfl_xor(x1, 3);  // from q^3
      if (q == 0){                   // x1=sig(i), xf=sig(f), xg=tanh(g), xo=sig(o)
        float co = C_state[b*512 + hfull];
        float cn = xf*co + x1*xg;
        float hn = xo * tanhf(cn);
        C_state[b*512 + hfull] = cn;
        unsigned short hb = f2bf(hn);
        HCnext[b*1024 + 512 + hfull] = hb;
        HCz[((size_t)b*32 + t)*1024 + hfull] = hb;
      }
    }
  }
}

// ---------------------------------------------------------------------------
// recurrence step 2: energy/softmax/ctx per batch row. grid 32 blocks (b)
// ---------------------------------------------------------------------------
__launch_bounds__(256, 1)
__global__ void k_attn(const unsigned short* __restrict__ memB,
                       const unsigned char* __restrict__ emask,
                       unsigned short* __restrict__ HCnext,
                       unsigned short* __restrict__ HCz,
                       float* __restrict__ Esave,
                       int t)
{
  int b = blockIdx.x;
  int tid = threadIdx.x, lane = tid & 63, w = tid >> 6;
  __shared__ float E_s[100];
  __shared__ float attn_s[100];
  float hreg[8];
  {
    short8 hv = *(const short8*)(HCnext + b*1024 + 512 + lane*8);
    #pragma unroll
    for (int i = 0; i < 8; ++i) hreg[i] = bf2f((unsigned short)hv[i]);
  }
  for (int s = w; s < 100; s += 4){
    short8 mv = *(const short8*)(memB + ((size_t)b*100 + s)*512 + lane*8);
    float a = 0.f;
    #pragma unroll
    for (int i = 0; i < 8; ++i) a = fmaf(hreg[i], bf2f((unsigned short)mv[i]), a);
    #pragma unroll
    for (int d = 1; d < 64; d <<= 1) a += __shfl_xor(a, d);
    if (lane == 0){
      float e = emask[b*100 + s] ? -INFV : a;
      E_s[s] = e;
      Esave[((size_t)b*32 + t)*100 + s] = e;
    }
  }
  __syncthreads();
  if (w == 0){
    float ea = (lane < 100) ? E_s[lane] : -INFV;
    float eb = (lane + 64 < 100) ? E_s[lane + 64] : -INFV;
    float m = fmaxf(ea, eb);
    #pragma unroll
    for (int d = 1; d < 64; d <<= 1) m = fmaxf(m, __shfl_xor(m, d));
    float p = ((lane < 100) ? expf(ea - m) : 0.f) + ((lane + 64 < 100) ? expf(eb - m) : 0.f);
    #pragma unroll
    for (int d = 1; d < 64; d <<= 1) p += __shfl_xor(p, d);
    float inv = 1.f / p;
    if (lane < 100)      attn_s[lane]      = expf(ea - m) * inv;
    if (lane + 64 < 100) attn_s[lane + 64] = expf(eb - m) * inv;
  }
  __syncthreads();
  for (int hh = tid; hh < 512; hh += 256){
    float a = 0.f;
    for (int s = 0; s < 100; ++s)
      a = fmaf(attn_s[s], bf2f(memB[((size_t)b*100 + s)*512 + hh]), a);
    unsigned short cbv = f2bf(a);
    HCnext[b*1024 + hh] = cbv;
    HCz[((size_t)b*32 + t)*1024 + 512 + hh] = cbv;
  }
}

// ---------------------------------------------------------------------------
// final: logits = Z @ WoT^T + b_out, fused pointer scatter-max + INF rules
// grid (352 col-tiles, 8 row-tiles), 256 thr, 128x128 tile, bf16 MFMA
// ---------------------------------------------------------------------------
__launch_bounds__(256, 2)
__global__ void k_logits(const unsigned short* __restrict__ Zbf,
                         const unsigned short* __restrict__ WoT,
                         const float* __restrict__ b_out,
                         const float* __restrict__ Esave,
                         const int* __restrict__ ext_src,
                         float* __restrict__ out)
{
  __shared__ char smem[128*128*4];   // 64 KB; tiles live in first 20 KB, smax reuses all
  char* smA = smem;                  // 128 rows x 64B, pitch 80
  char* smB = smem + 10240;
  int tid = threadIdx.x, lane = tid & 63;
  int w = tid >> 6, wr = w >> 1, wc = w & 1;
  int m0 = blockIdx.y * 128, n0 = blockIdx.x * 128;
  int l15 = lane & 15, lh = lane >> 4;
  f32x4 zero = {0.f,0.f,0.f,0.f};
  f32x4 acc[4][4];
  #pragma unroll
  for (int mi = 0; mi < 4; ++mi)
    #pragma unroll
    for (int ni = 0; ni < 4; ++ni) acc[mi][ni] = zero;

  for (int kc = 0; kc < 512; kc += 32){
    #pragma unroll
    for (int call = 0; call < 2; ++call){
      int o = call*4096 + tid*16;
      int r = o >> 6, cb = o & 63;
      short8 va = *(const short8*)((const char*)Zbf + (size_t)(m0 + r)*1024 + kc*2 + cb);
      *(short8*)(smA + r*80 + cb) = va;
      short8 vb = *(const short8*)((const char*)WoT + (size_t)(n0 + r)*1024 + kc*2 + cb);
      *(short8*)(smB + r*80 + cb) = vb;
    }
    __syncthreads();
    short8 af[4], bfv[4];
    #pragma unroll
    for (int mi = 0; mi < 4; ++mi) af[mi]  = *(const short8*)(smA + (wr*64 + mi*16 + l15)*80 + lh*16);
    #pragma unroll
    for (int ni = 0; ni < 4; ++ni) bfv[ni] = *(const short8*)(smB + (wc*64 + ni*16 + l15)*80 + lh*16);
    #pragma unroll
    for (int mi = 0; mi < 4; ++mi)
      #pragma unroll
      for (int ni = 0; ni < 4; ++ni)
        acc[mi][ni] = __builtin_amdgcn_mfma_f32_16x16x32_bf16(af[mi], bfv[ni], acc[mi][ni], 0, 0, 0);
    __syncthreads();
  }

  // scatter-max table over this tile's 128 cols, per row
  float* smax = (float*)smem;
  for (int i = tid; i < 128*128; i += 256) smax[i] = -INFV;
  __syncthreads();
  if (tid < 128){
    int rg = m0 + tid;
    int b = rg >> 5;
    const int* es = ext_src + b*100;
    const float* ev = Esave + (size_t)rg*100;
    float* row = smax + tid*128;
    for (int s = 0; s < 100; ++s){
      unsigned int d = (unsigned int)(es[s] - n0);
      if (d < 128u){
        float e = ev[s];
        if (e > -9e11f && e > row[d]) row[d] = e;
      }
    }
  }
  __syncthreads();

  #pragma unroll
  for (int mi = 0; mi < 4; ++mi){
    #pragma unroll
    for (int ni = 0; ni < 4; ++ni){
      #pragma unroll
      for (int j = 0; j < 4; ++j){
        int rl = wr*64 + mi*16 + 4*lh + j;
        int cl = wc*64 + ni*16 + l15;
        int cg = n0 + cl;
        if (cg < VE){
          float v = acc[mi][ni][j];
          float base = (cg < Vv) ? (v + b_out[cg]) : 0.f;   // OOV slots: ext part is exactly 0
          float sm = smax[rl*128 + cl];
          float o = base + (sm > -9e11f ? sm : 0.f);        // scat==-INF -> +0
          if (o == 0.f) o = -INFV;                          // out==0 -> -INF
          out[(size_t)(m0 + rl)*VE + cg] = o;
        }
      }
    }
  }
}

// ---------------------------------------------------------------------------
extern "C" void kernel_launch(void* const* d_in, const int* in_sizes, int n_in,
                              void* d_out, int out_size, void* d_ws, size_t ws_size,
                              hipStream_t stream)
{
  const int*   trg    = (const int*)  d_in[0];
  const int*   ext    = (const int*)  d_in[1];
  const float* h0     = (const float*)d_in[2];
  const float* c0     = (const float*)d_in[3];
  const float* tree   = (const float*)d_in[4];
  /* d_in[5] tree_enc_states: unused by reference */
  const float* enc    = (const float*)d_in[6];
  const unsigned char* emask = (const unsigned char*)d_in[7];
  const float* emb    = (const float*)d_in[8];
  const float* W_enc  = (const float*)d_in[9];
  const float* b_enc  = (const float*)d_in[10];
  const float* W_red  = (const float*)d_in[11];
  const float* b_red  = (const float*)d_in[12];
  const float* W_ih   = (const float*)d_in[13];
  const float* W_hh   = (const float*)d_in[14];
  const float* b_ih   = (const float*)d_in[15];
  const float* b_hh   = (const float*)d_in[16];
  const float* W_cat  = (const float*)d_in[17];
  const float* b_cat  = (const float*)d_in[18];
  const float* W_out  = (const float*)d_in[19];
  const float* b_out  = (const float*)d_in[20];
  float* out = (float*)d_out;

  char* ws = (char*)d_ws;
  size_t off = 0;
  auto alloc = [&](size_t bytes)->char*{
    char* p = ws + off; off = (off + bytes + 255) & ~(size_t)255; return p;
  };
  float*          memf = (float*)         alloc(3200ull*512*4);
  unsigned short* memB = (unsigned short*)alloc(3200ull*512*2);
  float*          EmbA = (float*)         alloc(1024ull*300*4);
  float*          X0   = (float*)         alloc(1024ull*300*4);
  float*          G1   = (float*)         alloc(1024ull*2048*4);
  float*          bsum = (float*)         alloc(2048*4);
  float*          Wf   = (float*)         alloc(512ull*2048*4);
  unsigned short* WgT  = (unsigned short*)alloc(2048ull*1024*2);
  unsigned short* WoT  = (unsigned short*)alloc(45056ull*512*2);
  unsigned short* HCa  = (unsigned short*)alloc(32*1024*2);
  unsigned short* HCb  = (unsigned short*)alloc(32*1024*2);
  float*          Cst  = (float*)         alloc(32*512*4);
  unsigned short* HCz  = (unsigned short*)alloc(1024ull*1024*2);
  unsigned short* Zbf  = (unsigned short*)alloc(1024ull*512*2);
  float*          Esave= (float*)         alloc(1024ull*100*4);

  // memories = concat(tree_output, encoder_outputs) @ W_enc + b_enc  [3200,512]
  k_gemm<false,false><<<dim3(8,50), 256, 0, stream>>>(tree, enc, 512, W_enc, b_enc,
                                                      memf, 3200, 512, 1024);
  k_cvt<<<(3200*512 + 255)/256, 256, 0, stream>>>(memf, memB, 3200*512);

  // G1 = (emb@W_red1 + b_red)@W_ih + (b_ih+b_hh)   [1024,2048]
  k_gather<<<(1024*300 + 255)/256, 256, 0, stream>>>(trg, emb, EmbA);
  k_gemm<false,false><<<dim3(5,16), 256, 0, stream>>>(EmbA, nullptr, 300, W_red, b_red,
                                                      X0, 1024, 300, 300);
  k_bsum<<<8, 256, 0, stream>>>(b_ih, b_hh, bsum);
  k_gemm<false,false><<<dim3(32,16), 256, 0, stream>>>(X0, nullptr, 300, W_ih, bsum,
                                                       G1, 1024, 2048, 300);
  // Wf = W_red2 @ W_ih   [512,2048]
  k_gemm<false,false><<<dim3(32,8), 256, 0, stream>>>(W_red + 300*300, nullptr, 300, W_ih,
                                                      nullptr, Wf, 512, 2048, 300);
  k_wgt<<<(2048*1024 + 255)/256, 256, 0, stream>>>(Wf, W_hh, WgT);
  k_wot<<<dim3(704,8), 256, 0, stream>>>(W_out, WoT);
  k_init<<<128, 256, 0, stream>>>(h0, c0, HCa, Cst);

  // sequential recurrence (state double-buffered by t parity)
  for (int t = 0; t < 32; ++t){
    unsigned short* hp = (t & 1) ? HCb : HCa;
    unsigned short* hn = (t & 1) ? HCa : HCb;
    k_gates<<<32, 256, 0, stream>>>(WgT, hp, hn, Cst, G1, HCz, t);
    k_attn <<<32, 256, 0, stream>>>(memB, emask, hn, HCz, Esave, t);
  }

  // Z = tanh([h|ctx] @ W_cat + b_cat)  -> bf16
  k_gemm<true,true><<<dim3(8,16), 256, 0, stream>>>(HCz, nullptr, 1024, W_cat, b_cat,
                                                    Zbf, 1024, 512, 1024);
  // logits + pointer scatter + INF rules -> out
  k_logits<<<dim3(352,8), 256, 0, stream>>>(Zbf, WoT, b_out, Esave, ext, out);
}

// Round 2
// 1951.820 us; speedup vs baseline: 1.1852x; 1.1852x over previous
//
#include <hip/hip_runtime.h>
#include <hip/hip_bf16.h>
#include <stdint.h>

typedef __hip_bfloat16 bf16;
typedef __attribute__((ext_vector_type(8))) short short8;
typedef __attribute__((ext_vector_type(4))) float f32x4;

#define INFV 1e12f

constexpr int Vv = 45000;
constexpr int VE = 45010;

static __device__ __forceinline__ float bf2f(unsigned short u){
  union{ unsigned int i; float f; } w; w.i = ((unsigned int)u) << 16; return w.f;
}
static __device__ __forceinline__ unsigned short f2bf(float x){
  union { __hip_bfloat16 h; unsigned short u; } w; w.h = __float2bfloat16(x); return w.u;
}

// ---------------------------------------------------------------------------
// Generic bf16 MFMA GEMM: C[M,N] = A[M,K] @ B^T (B stored [N][K]) + bias
// A: bf16 [M][lda], B: bf16 [NB rows][ldb], K multiple of 32.
// mode 0: f32 out; 1: bf16 out; 2: bf16 tanh out. Cols [N,NZ) written as 0.
// ---------------------------------------------------------------------------
__launch_bounds__(256, 2)
__global__ void k_mm(const unsigned short* __restrict__ A, int lda,
                     const unsigned short* __restrict__ B, int ldb, int NB,
                     const float* __restrict__ bias,
                     void* __restrict__ C, int ldc,
                     int M, int N, int NZ, int K, int mode)
{
  __shared__ char smem[20480];
  char* smA = smem;          // 128 rows x 64B, pitch 80
  char* smB = smem + 10240;
  int tid = threadIdx.x, lane = tid & 63;
  int w = tid >> 6, wr = w >> 1, wc = w & 1;
  int m0 = blockIdx.y * 128, n0 = blockIdx.x * 128;
  int l15 = lane & 15, lh = lane >> 4;
  f32x4 zero = {0.f,0.f,0.f,0.f};
  f32x4 acc[4][4];
  #pragma unroll
  for (int mi = 0; mi < 4; ++mi)
    #pragma unroll
    for (int ni = 0; ni < 4; ++ni) acc[mi][ni] = zero;
  short8 z8 = {0,0,0,0,0,0,0,0};

  for (int kc = 0; kc < K; kc += 32){
    #pragma unroll
    for (int call = 0; call < 2; ++call){
      int o = call*4096 + tid*16;
      int r = o >> 6, cb = o & 63;
      short8 va = z8, vb = z8;
      if (m0 + r < M)  va = *(const short8*)((const char*)A + ((size_t)(m0+r)*lda + kc)*2 + cb);
      if (n0 + r < NB) vb = *(const short8*)((const char*)B + ((size_t)(n0+r)*ldb + kc)*2 + cb);
      *(short8*)(smA + r*80 + cb) = va;
      *(short8*)(smB + r*80 + cb) = vb;
    }
    __syncthreads();
    short8 af[4], bfv[4];
    #pragma unroll
    for (int mi = 0; mi < 4; ++mi) af[mi]  = *(const short8*)(smA + (wr*64 + mi*16 + l15)*80 + lh*16);
    #pragma unroll
    for (int ni = 0; ni < 4; ++ni) bfv[ni] = *(const short8*)(smB + (wc*64 + ni*16 + l15)*80 + lh*16);
    #pragma unroll
    for (int mi = 0; mi < 4; ++mi)
      #pragma unroll
      for (int ni = 0; ni < 4; ++ni)
        acc[mi][ni] = __builtin_amdgcn_mfma_f32_16x16x32_bf16(af[mi], bfv[ni], acc[mi][ni], 0, 0, 0);
    __syncthreads();
  }

  #pragma unroll
  for (int mi = 0; mi < 4; ++mi){
    #pragma unroll
    for (int ni = 0; ni < 4; ++ni){
      #pragma unroll
      for (int j = 0; j < 4; ++j){
        int gr = m0 + wr*64 + mi*16 + 4*lh + j;
        int cg = n0 + wc*64 + ni*16 + l15;
        if (gr < M && cg < NZ){
          float v = (cg < N) ? acc[mi][ni][j] + (bias ? bias[cg] : 0.f) : 0.f;
          if (mode == 0) ((float*)C)[(size_t)gr*ldc + cg] = v;
          else {
            if (mode == 2) v = tanhf(v);
            ((unsigned short*)C)[(size_t)gr*ldc + cg] = f2bf(v);
          }
        }
      }
    }
  }
}

// ---------------------------------------------------------------------------
// prep kernels
// ---------------------------------------------------------------------------
// transpose f32 [K][N] (row stride ldin) -> bf16 [N2][K2], zero-padded
__launch_bounds__(256)
__global__ void k_tbf(const float* __restrict__ in, int ldin,
                      unsigned short* __restrict__ out,
                      int K, int N, int K2, int N2)
{
  __shared__ float tl[64][65];
  int n0 = blockIdx.x * 64, k0 = blockIdx.y * 64;
  int tid = threadIdx.x;
  for (int idx = tid; idx < 64*64; idx += 256){
    int r = idx >> 6, c = idx & 63;       // r=k-local, c=n-local
    int gk = k0 + r, gn = n0 + c;
    tl[r][c] = (gk < K && gn < N) ? in[(size_t)gk*ldin + gn] : 0.f;
  }
  __syncthreads();
  for (int idx = tid; idx < 64*64; idx += 256){
    int r = idx >> 6, c = idx & 63;       // r=n-local, c=k-local
    int gn = n0 + r, gk = k0 + c;
    if (gn < N2 && gk < K2) out[(size_t)gn*K2 + gk] = f2bf(tl[c][r]);
  }
}

// Acat[3200][1024] bf16 = concat(tree, enc)
__global__ void k_cat2bf(const float* __restrict__ tree, const float* __restrict__ enc,
                         unsigned short* __restrict__ Acat){
  int i = blockIdx.x*256 + threadIdx.x;
  if (i >= 3200*1024) return;
  int r = i >> 10, c = i & 1023;
  float v = (c < 512) ? tree[(size_t)r*512 + c] : enc[(size_t)r*512 + (c - 512)];
  Acat[i] = f2bf(v);
}

// EmbAb[1024][320] bf16 gather, K-padded
__global__ void k_gatherbf(const int* __restrict__ trg, const float* __restrict__ emb,
                           unsigned short* __restrict__ EmbAb){
  int i = blockIdx.x*256 + threadIdx.x;
  if (i >= 1024*320) return;
  int r = i / 320, c = i - r*320;
  EmbAb[i] = (c < 300) ? f2bf(emb[(size_t)trg[r]*300 + c]) : (unsigned short)0;
}

// Wred2b[512][320] bf16 = W_red rows 300..811, K-padded
__global__ void k_cvtpad(const float* __restrict__ in, unsigned short* __restrict__ out){
  int i = blockIdx.x*256 + threadIdx.x;
  if (i >= 512*320) return;
  int r = i / 320, c = i - r*320;
  out[i] = (c < 300) ? f2bf(in[(size_t)r*300 + c]) : (unsigned short)0;
}

__global__ void k_bsum(const float* __restrict__ a, const float* __restrict__ b,
                       float* __restrict__ o){
  int i = blockIdx.x*256 + threadIdx.x;
  if (i < 2048) o[i] = a[i] + b[i];
}

// WgT[c'][k] = bf16 of [Wf;W_hh][k][c], c' = 4*h+q
__global__ void k_wgt(const float* __restrict__ Wf, const float* __restrict__ W_hh,
                      unsigned short* __restrict__ WgT){
  int idx = blockIdx.x*256 + threadIdx.x;
  if (idx >= 2048*1024) return;
  int cp = idx >> 10, k = idx & 1023;
  int c = (cp & 3)*512 + (cp >> 2);
  float v = (k < 512) ? Wf[(size_t)k*2048 + c] : W_hh[(size_t)(k-512)*2048 + c];
  WgT[idx] = f2bf(v);
}

__global__ void k_init(const float* __restrict__ h0, const float* __restrict__ c0,
                       unsigned short* __restrict__ HCa, float* __restrict__ Cst){
  int i = blockIdx.x*256 + threadIdx.x;
  if (i < 32*1024){
    int b = i >> 10, k = i & 1023;
    HCa[i] = (k < 512) ? f2bf(0.f) : f2bf(h0[b*512 + (k - 512)]);
  }
  if (i < 32*512) Cst[i] = c0[i];
}

// ---------------------------------------------------------------------------
// recurrence step 1: gates = G1[:,t] + [ctx|h] @ WgT^T, LSTM cell -> h,c
// ---------------------------------------------------------------------------
__launch_bounds__(256, 1)
__global__ void k_gates(const unsigned short* __restrict__ WgT,
                        const unsigned short* __restrict__ HCprev,
                        unsigned short* __restrict__ HCnext,
                        float* __restrict__ C_state,
                        const float* __restrict__ G1,
                        unsigned short* __restrict__ HCz,
                        int t)
{
  __shared__ char Bsm[64*272];
  int tid = threadIdx.x;
  int lane = tid & 63, w2 = tid >> 6;
  int blk = blockIdx.x;
  int l15 = lane & 15, lh = lane >> 4;
  f32x4 zero = {0.f,0.f,0.f,0.f};
  f32x4 acc0 = zero, acc1 = zero;
  const char* Ab = (const char*)HCprev;

  for (int kc = 0; kc < 1024; kc += 128){
    #pragma unroll
    for (int call = 0; call < 4; ++call){
      int o = call*4096 + tid*16;
      int r = o >> 8, cb = o & 255;
      short8 v = *(const short8*)((const char*)WgT + (size_t)(blk*64 + r)*2048 + kc*2 + cb);
      *(short8*)(Bsm + r*272 + cb) = v;
    }
    __syncthreads();
    #pragma unroll
    for (int ks = 0; ks < 4; ++ks){
      short8 a0 = *(const short8*)(Ab + (size_t)l15*2048      + (kc + ks*32)*2 + lh*16);
      short8 a1 = *(const short8*)(Ab + (size_t)(l15+16)*2048 + (kc + ks*32)*2 + lh*16);
      int br = w2*16 + l15;
      short8 bfr = *(const short8*)(Bsm + br*272 + ks*64 + lh*16);
      acc0 = __builtin_amdgcn_mfma_f32_16x16x32_bf16(a0, bfr, acc0, 0, 0, 0);
      acc1 = __builtin_amdgcn_mfma_f32_16x16x32_bf16(a1, bfr, acc1, 0, 0, 0);
    }
    __syncthreads();
  }

  int cg = blk*64 + w2*16 + l15;
  int hfull = cg >> 2, q = cg & 3;
  #pragma unroll
  for (int f = 0; f < 2; ++f){
    #pragma unroll
    for (int j = 0; j < 4; ++j){
      int b = f*16 + 4*lh + j;
      float g = (f ? acc1[j] : acc0[j]) + G1[((size_t)b*32 + t)*2048 + q*512 + hfull];
      float x1 = (q == 2) ? tanhf(g) : 1.f/(1.f + expf(-g));
      float xg = __shfl_xor(x1, 2);
      float xf = __shfl_xor(x1, 1);
      float xo = __shfl_xor(x1, 3);
      if (q == 0){
        float co = C_state[b*512 + hfull];
        float cn = xf*co + x1*xg;
        float hn = xo * tanhf(cn);
        C_state[b*512 + hfull] = cn;
        unsigned short hb = f2bf(hn);
        HCnext[b*1024 + 512 + hfull] = hb;
        HCz[((size_t)b*32 + t)*1024 + hfull] = hb;
      }
    }
  }
}

// ---------------------------------------------------------------------------
// recurrence step 2: energy/softmax/ctx per batch row
// ---------------------------------------------------------------------------
__launch_bounds__(256, 1)
__global__ void k_attn(const unsigned short* __restrict__ memB,
                       const unsigned char* __restrict__ emask,
                       unsigned short* __restrict__ HCnext,
                       unsigned short* __restrict__ HCz,
                       float* __restrict__ Esave,
                       int t)
{
  int b = blockIdx.x;
  int tid = threadIdx.x, lane = tid & 63, w = tid >> 6;
  __shared__ float E_s[100];
  __shared__ float attn_s[100];
  float hreg[8];
  {
    short8 hv = *(const short8*)(HCnext + b*1024 + 512 + lane*8);
    #pragma unroll
    for (int i = 0; i < 8; ++i) hreg[i] = bf2f((unsigned short)hv[i]);
  }
  for (int s = w; s < 100; s += 4){
    short8 mv = *(const short8*)(memB + ((size_t)b*100 + s)*512 + lane*8);
    float a = 0.f;
    #pragma unroll
    for (int i = 0; i < 8; ++i) a = fmaf(hreg[i], bf2f((unsigned short)mv[i]), a);
    #pragma unroll
    for (int d = 1; d < 64; d <<= 1) a += __shfl_xor(a, d);
    if (lane == 0){
      float e = emask[b*100 + s] ? -INFV : a;
      E_s[s] = e;
      Esave[((size_t)b*32 + t)*100 + s] = e;
    }
  }
  __syncthreads();
  if (w == 0){
    float ea = (lane < 100) ? E_s[lane] : -INFV;
    float eb = (lane + 64 < 100) ? E_s[lane + 64] : -INFV;
    float m = fmaxf(ea, eb);
    #pragma unroll
    for (int d = 1; d < 64; d <<= 1) m = fmaxf(m, __shfl_xor(m, d));
    float p = ((lane < 100) ? expf(ea - m) : 0.f) + ((lane + 64 < 100) ? expf(eb - m) : 0.f);
    #pragma unroll
    for (int d = 1; d < 64; d <<= 1) p += __shfl_xor(p, d);
    float inv = 1.f / p;
    if (lane < 100)      attn_s[lane]      = expf(ea - m) * inv;
    if (lane + 64 < 100) attn_s[lane + 64] = expf(eb - m) * inv;
  }
  __syncthreads();
  for (int hh = tid; hh < 512; hh += 256){
    float a = 0.f;
    for (int s = 0; s < 100; ++s)
      a = fmaf(attn_s[s], bf2f(memB[((size_t)b*100 + s)*512 + hh]), a);
    unsigned short cbv = f2bf(a);
    HCnext[b*1024 + hh] = cbv;
    HCz[((size_t)b*32 + t)*1024 + 512 + hh] = cbv;
  }
}

// ---------------------------------------------------------------------------
// final: logits = Z @ WoT^T + b_out, fused pointer scatter-max + INF rules
// 32 KB LDS (two-half epilogue) -> 5 blocks/CU
// ---------------------------------------------------------------------------
__launch_bounds__(256, 4)
__global__ void k_logits(const unsigned short* __restrict__ Zbf,
                         const unsigned short* __restrict__ WoT,
                         const float* __restrict__ b_out,
                         const float* __restrict__ Esave,
                         const int* __restrict__ ext_src,
                         float* __restrict__ out)
{
  __shared__ char smem[32768];
  char* smA = smem;                  // 128 rows x 64B, pitch 80
  char* smB = smem + 10240;
  int tid = threadIdx.x, lane = tid & 63;
  int w = tid >> 6, wr = w >> 1, wc = w & 1;
  int m0 = blockIdx.y * 128, n0 = blockIdx.x * 128;
  int l15 = lane & 15, lh = lane >> 4;
  f32x4 zero = {0.f,0.f,0.f,0.f};
  f32x4 acc[4][4];
  #pragma unroll
  for (int mi = 0; mi < 4; ++mi)
    #pragma unroll
    for (int ni = 0; ni < 4; ++ni) acc[mi][ni] = zero;

  for (int kc = 0; kc < 512; kc += 32){
    #pragma unroll
    for (int call = 0; call < 2; ++call){
      int o = call*4096 + tid*16;
      int r = o >> 6, cb = o & 63;
      short8 va = *(const short8*)((const char*)Zbf + (size_t)(m0 + r)*1024 + kc*2 + cb);
      *(short8*)(smA + r*80 + cb) = va;
      short8 vb = *(const short8*)((const char*)WoT + (size_t)(n0 + r)*1024 + kc*2 + cb);
      *(short8*)(smB + r*80 + cb) = vb;
    }
    __syncthreads();
    short8 af[4], bfv[4];
    #pragma unroll
    for (int mi = 0; mi < 4; ++mi) af[mi]  = *(const short8*)(smA + (wr*64 + mi*16 + l15)*80 + lh*16);
    #pragma unroll
    for (int ni = 0; ni < 4; ++ni) bfv[ni] = *(const short8*)(smB + (wc*64 + ni*16 + l15)*80 + lh*16);
    #pragma unroll
    for (int mi = 0; mi < 4; ++mi)
      #pragma unroll
      for (int ni = 0; ni < 4; ++ni)
        acc[mi][ni] = __builtin_amdgcn_mfma_f32_16x16x32_bf16(af[mi], bfv[ni], acc[mi][ni], 0, 0, 0);
    __syncthreads();
  }

  // scatter-max + epilogue in two 64-row halves (smax table 64x128 f32 = 32 KB)
  float* smax = (float*)smem;
  for (int half = 0; half < 2; ++half){
    for (int i = tid; i < 64*128; i += 256) smax[i] = -INFV;
    __syncthreads();
    if (tid < 64){
      int rg = m0 + half*64 + tid;
      int b = rg >> 5;
      const int* es = ext_src + b*100;
      const float* ev = Esave + (size_t)rg*100;
      float* row = smax + tid*128;
      for (int s = 0; s < 100; ++s){
        unsigned int d = (unsigned int)(es[s] - n0);
        if (d < 128u){
          float e = ev[s];
          if (e > -9e11f && e > row[d]) row[d] = e;
        }
      }
    }
    __syncthreads();
    if (wr == half){
      #pragma unroll
      for (int mi = 0; mi < 4; ++mi){
        #pragma unroll
        for (int ni = 0; ni < 4; ++ni){
          #pragma unroll
          for (int j = 0; j < 4; ++j){
            int rll = mi*16 + 4*lh + j;          // row-local within half
            int cl = wc*64 + ni*16 + l15;
            int cg = n0 + cl;
            if (cg < VE){
              float v = acc[mi][ni][j];
              float base = (cg < Vv) ? (v + b_out[cg]) : 0.f;
              float sm = smax[rll*128 + cl];
              float o = base + (sm > -9e11f ? sm : 0.f);
              if (o == 0.f) o = -INFV;
              out[(size_t)(m0 + half*64 + rll)*VE + cg] = o;
            }
          }
        }
      }
    }
    __syncthreads();
  }
}

// ---------------------------------------------------------------------------
extern "C" void kernel_launch(void* const* d_in, const int* in_sizes, int n_in,
                              void* d_out, int out_size, void* d_ws, size_t ws_size,
                              hipStream_t stream)
{
  const int*   trg    = (const int*)  d_in[0];
  const int*   ext    = (const int*)  d_in[1];
  const float* h0     = (const float*)d_in[2];
  const float* c0     = (const float*)d_in[3];
  const float* tree   = (const float*)d_in[4];
  const float* enc    = (const float*)d_in[6];
  const unsigned char* emask = (const unsigned char*)d_in[7];
  const float* emb    = (const float*)d_in[8];
  const float* W_enc  = (const float*)d_in[9];
  const float* b_enc  = (const float*)d_in[10];
  const float* W_red  = (const float*)d_in[11];
  const float* b_red  = (const float*)d_in[12];
  const float* W_ih   = (const float*)d_in[13];
  const float* W_hh   = (const float*)d_in[14];
  const float* b_ih   = (const float*)d_in[15];
  const float* b_hh   = (const float*)d_in[16];
  const float* W_cat  = (const float*)d_in[17];
  const float* b_cat  = (const float*)d_in[18];
  const float* W_out  = (const float*)d_in[19];
  const float* b_out  = (const float*)d_in[20];
  float* out = (float*)d_out;

  char* ws = (char*)d_ws;
  size_t off = 0;
  auto alloc = [&](size_t bytes)->char*{
    char* p = ws + off; off = (off + bytes + 255) & ~(size_t)255; return p;
  };
  unsigned short* Acat  = (unsigned short*)alloc(3200ull*1024*2);
  unsigned short* WencT = (unsigned short*)alloc(512ull*1024*2);
  unsigned short* memB  = (unsigned short*)alloc(3200ull*512*2);
  unsigned short* EmbAb = (unsigned short*)alloc(1024ull*320*2);
  unsigned short* WredT1= (unsigned short*)alloc(320ull*320*2);
  unsigned short* X0b   = (unsigned short*)alloc(1024ull*320*2);
  unsigned short* WihT  = (unsigned short*)alloc(2048ull*320*2);
  float*          G1    = (float*)         alloc(1024ull*2048*4);
  float*          bsum  = (float*)         alloc(2048*4);
  unsigned short* Wred2b= (unsigned short*)alloc(512ull*320*2);
  unsigned short* WgT   = (unsigned short*)alloc(2048ull*1024*2);
  unsigned short* WoT   = (unsigned short*)alloc(45056ull*512*2);
  unsigned short* WcatT = (unsigned short*)alloc(512ull*1024*2);
  unsigned short* HCa   = (unsigned short*)alloc(32*1024*2);
  unsigned short* HCb   = (unsigned short*)alloc(32*1024*2);
  float*          Cst   = (float*)         alloc(32*512*4);
  unsigned short* HCz   = (unsigned short*)alloc(1024ull*1024*2);
  unsigned short* Zbf   = (unsigned short*)alloc(1024ull*512*2);
  float*          Esave = (float*)         alloc(1024ull*100*4);
  float*          Wf    = (float*)Acat;   // alias: Acat dead after memB GEMM

  // memories -> memB bf16 [3200][512]
  k_cat2bf<<<12800, 256, 0, stream>>>(tree, enc, Acat);
  k_tbf<<<dim3(8,16), 256, 0, stream>>>(W_enc, 512, WencT, 1024, 512, 1024, 512);
  k_mm<<<dim3(4,25), 256, 0, stream>>>(Acat, 1024, WencT, 1024, 512, b_enc,
                                       memB, 512, 3200, 512, 512, 1024, 1);

  // G1 = (emb@W_red1 + b_red)@W_ih + (b_ih+b_hh)   [1024,2048] f32
  k_gatherbf<<<1280, 256, 0, stream>>>(trg, emb, EmbAb);
  k_tbf<<<dim3(5,5), 256, 0, stream>>>(W_red, 300, WredT1, 300, 300, 320, 320);
  k_tbf<<<dim3(32,5), 256, 0, stream>>>(W_ih, 2048, WihT, 300, 2048, 320, 2048);
  k_bsum<<<8, 256, 0, stream>>>(b_ih, b_hh, bsum);
  k_mm<<<dim3(3,8), 256, 0, stream>>>(EmbAb, 320, WredT1, 320, 320, b_red,
                                      X0b, 320, 1024, 300, 320, 320, 1);
  k_mm<<<dim3(16,8), 256, 0, stream>>>(X0b, 320, WihT, 320, 2048, bsum,
                                       G1, 2048, 1024, 2048, 2048, 320, 0);

  // Wf = W_red2 @ W_ih  [512,2048] f32 (into Acat space), then WgT
  k_cvtpad<<<640, 256, 0, stream>>>(W_red + 300*300, Wred2b);
  k_mm<<<dim3(16,4), 256, 0, stream>>>(Wred2b, 320, WihT, 320, 2048, nullptr,
                                       Wf, 2048, 512, 2048, 2048, 320, 0);
  k_wgt<<<8192, 256, 0, stream>>>(Wf, W_hh, WgT);

  // transposed weights for output path
  k_tbf<<<dim3(704,8), 256, 0, stream>>>(W_out, 45000, WoT, 512, 45000, 512, 45056);
  k_tbf<<<dim3(8,16), 256, 0, stream>>>(W_cat, 512, WcatT, 1024, 512, 1024, 512);
  k_init<<<128, 256, 0, stream>>>(h0, c0, HCa, Cst);

  // sequential recurrence
  for (int t = 0; t < 32; ++t){
    unsigned short* hp = (t & 1) ? HCb : HCa;
    unsigned short* hn = (t & 1) ? HCa : HCb;
    k_gates<<<32, 256, 0, stream>>>(WgT, hp, hn, Cst, G1, HCz, t);
    k_attn <<<32, 256, 0, stream>>>(memB, emask, hn, HCz, Esave, t);
  }

  // Z = tanh([h|ctx] @ W_cat + b_cat) -> bf16
  k_mm<<<dim3(4,8), 256, 0, stream>>>(HCz, 1024, WcatT, 1024, 512, b_cat,
                                      Zbf, 512, 1024, 512, 512, 1024, 2);
  // logits + pointer scatter + INF rules
  k_logits<<<dim3(352,8), 256, 0, stream>>>(Zbf, WoT, b_out, Esave, ext, out);
}